// Round 2
// baseline (409.458 us; speedup 1.0000x reference)
//
#include <hip/hip_runtime.h>
#include <stdint.h>

// DetectPeaksTM: per row of nt=8192 fp32, x=|xcorr|, sliding max window K=301
// (pad 150), scores = x where x==windowmax else 0, top-2 (score, idx).
// Outputs concatenated: [nrows*2] f32 scores, then [nrows*2] indices written
// as float values (harness reads whole d_out as float32; idx<8192 exact).
//
// R2 structure (one 256-thr block per row, reg-resident values, tiny LDS):
//  P1: 8x float4 coalesced loads -> abs in regs; per-lane float4 max -> LDS
//      m4[2048]; 8-lane shuffle tree -> segment(32) maxes m[256].
//  P2: candidate = elem equal to its own 32-seg max (own seg is always inside
//      the +-150 window -> every true peak is a candidate; ~256/row).
//      Inline verify: interior full-segment max via m[] (~9 reads) with early
//      reject (own seg included, so interior_max>v kills ~8/9 of candidates);
//      survivors (~28/row) check window edges via m4[] blocks + <=3 scalar
//      global re-reads per edge (L1/L2-warm).
//  P3: top-2 via monotone key (bits(v)<<32)|(8191-t) (value desc, idx asc on
//      ties == jax.lax.top_k order), wave shuffle + tiny LDS reduce.

#define NT 8192
#define RADIUS 150
#define NTHREADS 256

__global__ __launch_bounds__(256) void detect_peaks_kernel(
    const float* __restrict__ x, float* __restrict__ out, int nrows)
{
    const int row = blockIdx.x;
    const int tid = threadIdx.x;

    __shared__ float m4[NT / 4];   // max of each aligned float4  (8 KB)
    __shared__ float m[NT / 32];   // max of each aligned 32-seg  (1 KB)
    __shared__ unsigned long long wred[8];

    const float* grow = x + (size_t)row * NT;
    const float4* g4 = (const float4*)grow;

    // ---- P1: load + abs + hierarchical maxes ----
    float4 vv[8];
#pragma unroll
    for (int it = 0; it < 8; ++it) vv[it] = g4[it * 256 + tid];   // issue all loads early

    float cms[8];
#pragma unroll
    for (int it = 0; it < 8; ++it) {
        float4 v = vv[it];
        v.x = fabsf(v.x); v.y = fabsf(v.y); v.z = fabsf(v.z); v.w = fabsf(v.w);
        vv[it] = v;
        const int c = it * 256 + tid;           // float4 index
        float cm4 = fmaxf(fmaxf(v.x, v.y), fmaxf(v.z, v.w));
        m4[c] = cm4;
        // lanes 8k..8k+7 (same c>>3) hold the 8 float4 chunks of one segment
        float cm = fmaxf(cm4, __shfl_xor(cm4, 1));
        cm = fmaxf(cm, __shfl_xor(cm, 2));
        cm = fmaxf(cm, __shfl_xor(cm, 4));
        cms[it] = cm;
        if ((tid & 7) == 0) m[c >> 3] = cm;
    }
    __syncthreads();

    // ---- P2: inline candidate verification ----
    unsigned long long k1 = 0ull, k2 = 0ull;

#pragma unroll
    for (int it = 0; it < 8; ++it) {
        const float cm = cms[it];
        const float4 v = vv[it];
        const int base = (it * 256 + tid) * 4;
#pragma unroll
        for (int e = 0; e < 4; ++e) {
            const float val = (e == 0) ? v.x : (e == 1) ? v.y : (e == 2) ? v.z : v.w;
            if (val != cm) continue;            // not its segment's max -> not a peak
            const int t = base + e;
            const int l = max(t - RADIUS, 0);
            const int r = min(t + RADIUS, NT - 1);
            const int il = l >> 5, ir = r >> 5;
            // interior full segments (includes t's own seg, so im >= val)
            float im = 0.0f;
            for (int s = il + 1; s < ir; ++s) im = fmaxf(im, m[s]);
            if (im > val) continue;             // beaten inside window: reject
            // edges at float4 granularity + <=3 scalar global re-reads each
            float em = 0.0f;
            {   // head: [l, (il+1)*32)
                const int le4 = (il + 1) << 3;  // end float4 block (exclusive)
                const int fb = (l + 3) >> 2;    // first full float4 block
                for (int u = l; u < fb * 4; ++u) em = fmaxf(em, fabsf(grow[u]));
                for (int b = fb; b < le4; ++b) em = fmaxf(em, m4[b]);
            }
            {   // tail: [ir*32, r]
                const int rs4 = ir << 3;
                const int re = (r + 1) & ~3;    // end of full blocks
                for (int b = rs4; b < (re >> 2); ++b) em = fmaxf(em, m4[b]);
                for (int u = re; u <= r; ++u) em = fmaxf(em, fabsf(grow[u]));
            }
            if (em > val) continue;
            const unsigned long long key =
                ((unsigned long long)__float_as_uint(val) << 32) |
                (unsigned)(NT - 1 - t);
            if (key > k1) { k2 = k1; k1 = key; }
            else if (key > k2) { k2 = key; }
        }
    }

    // ---- P3: top-2 reduction (wave shuffle, then 4 waves via LDS) ----
#pragma unroll
    for (int off = 32; off >= 1; off >>= 1) {
        unsigned long long o1 = __shfl_down(k1, off);
        unsigned long long o2 = __shfl_down(k2, off);
        unsigned long long hi = (k1 > o1) ? k1 : o1;
        unsigned long long lo = (k1 > o1) ? o1 : k1;
        unsigned long long s2 = (k2 > o2) ? k2 : o2;
        k1 = hi;
        k2 = (lo > s2) ? lo : s2;
    }
    const int wave = tid >> 6;
    if ((tid & 63) == 0) { wred[wave * 2] = k1; wred[wave * 2 + 1] = k2; }
    __syncthreads();

    if (tid == 0) {
        unsigned long long a1 = wred[0], a2 = wred[1];
        for (int w = 1; w < 4; ++w) {
            unsigned long long o1 = wred[w * 2], o2 = wred[w * 2 + 1];
            unsigned long long hi = (a1 > o1) ? a1 : o1;
            unsigned long long lo = (a1 > o1) ? o1 : a1;
            unsigned long long s2 = (a2 > o2) ? a2 : o2;
            a1 = hi;
            a2 = (lo > s2) ? lo : s2;
        }
        float s1v, s2v; int i1, i2;
        if (a1 == 0ull) { s1v = 0.0f; i1 = 0; }
        else {
            s1v = __uint_as_float((unsigned)(a1 >> 32));
            i1 = (NT - 1) - (int)(a1 & 0xffffffffull);
        }
        if (a2 == 0ull) {   // <2 peaks: second entry is first zero-score slot
            s2v = 0.0f;
            i2 = (i1 == 0) ? 1 : 0;
        } else {
            s2v = __uint_as_float((unsigned)(a2 >> 32));
            i2 = (NT - 1) - (int)(a2 & 0xffffffffull);
        }
        out[row * 2 + 0] = s1v;
        out[row * 2 + 1] = s2v;
        float* oi = out + (size_t)nrows * 2;
        oi[row * 2 + 0] = (float)i1;
        oi[row * 2 + 1] = (float)i2;
    }
}

extern "C" void kernel_launch(void* const* d_in, const int* in_sizes, int n_in,
                              void* d_out, int out_size, void* d_ws, size_t ws_size,
                              hipStream_t stream) {
    const float* x = (const float*)d_in[0];
    // d_in[1] = nlag (unused by the reference)
    float* out = (float*)d_out;
    const int nrows = in_sizes[0] / NT;  // 32*3*64 = 6144
    detect_peaks_kernel<<<nrows, NTHREADS, 0, stream>>>(x, out, nrows);
}

// Round 3
// 277.342 us; speedup vs baseline: 1.4764x; 1.4764x over previous
//
#include <hip/hip_runtime.h>
#include <stdint.h>

// DetectPeaksTM: per row of nt=8192 fp32, x=|xcorr|, sliding max window K=301
// (pad 150), scores = x where x==windowmax else 0, top-2 (score, idx).
// Outputs concatenated: [nrows*2] f32 scores, then [nrows*2] indices written
// as float values (harness reads whole d_out as float32; idx<8192 exact).
//
// R3: kill the serial dependent-LDS loops that made R2 VALU/latency-bound.
//  P1: 8x float4 loads -> abs; m4[2048] (float4 maxes), m[256] (32-seg maxes)
//      via 8-lane shuffle tree; per-lane 32-bit candidate mask (elem == its
//      own segment max; own segment is always inside the +-150 window, so
//      every true peak is a candidate).
//  P2: per-lane ctz loop over candidate bits (~Poisson(1)/lane -> ~5-6 wave
//      iterations). Each check uses FIXED-count, independent, clamped+masked
//      LDS reads (single waitcnt + tree max):
//       tier1: 9 interior segment maxes (includes own seg) -> reject if > val
//       tier2: 16 m4 superset-edge blocks -> accept if superset max == val
//       tier3 (rare ~0.5/row): exact fringe via <=8 scalar global re-reads
//  P3: top-2 via monotone key (bits(v)<<32)|(8191-t) (value desc, idx asc on
//      ties == jax.lax.top_k order), wave shuffle + tiny LDS reduce.

#define NT 8192
#define RADIUS 150
#define NTHREADS 256

__global__ __launch_bounds__(256) void detect_peaks_kernel(
    const float* __restrict__ x, float* __restrict__ out, int nrows)
{
    const int row = blockIdx.x;
    const int tid = threadIdx.x;

    __shared__ float m4[NT / 4];   // max of each aligned float4  (8 KB)
    __shared__ float m[NT / 32];   // max of each aligned 32-seg  (1 KB)
    __shared__ unsigned long long wred[8];

    const float* grow = x + (size_t)row * NT;
    const float4* g4 = (const float4*)grow;

    // ---- P1: load + abs + hierarchical maxes + candidate mask ----
    float4 vv[8];
#pragma unroll
    for (int it = 0; it < 8; ++it) vv[it] = g4[it * 256 + tid];

    unsigned int cmask = 0u;
#pragma unroll
    for (int it = 0; it < 8; ++it) {
        float4 v = vv[it];
        v.x = fabsf(v.x); v.y = fabsf(v.y); v.z = fabsf(v.z); v.w = fabsf(v.w);
        const int c = it * 256 + tid;           // float4 index
        const float cm4 = fmaxf(fmaxf(v.x, v.y), fmaxf(v.z, v.w));
        m4[c] = cm4;
        // lanes 8k..8k+7 (same c>>3) hold the 8 float4 chunks of one segment
        float cm = fmaxf(cm4, __shfl_xor(cm4, 1));
        cm = fmaxf(cm, __shfl_xor(cm, 2));
        cm = fmaxf(cm, __shfl_xor(cm, 4));
        if ((tid & 7) == 0) m[c >> 3] = cm;
        cmask |= (v.x == cm ? 1u : 0u) << (it * 4 + 0);
        cmask |= (v.y == cm ? 1u : 0u) << (it * 4 + 1);
        cmask |= (v.z == cm ? 1u : 0u) << (it * 4 + 2);
        cmask |= (v.w == cm ? 1u : 0u) << (it * 4 + 3);
    }
    __syncthreads();

    // ---- P2: candidate verification (batched LDS reads, no serial chains) ----
    unsigned long long k1 = 0ull, k2 = 0ull;
    unsigned int mask = cmask;

    while (__ballot(mask != 0u) != 0ull) {
        const bool active = (mask != 0u);
        int i = 0;
        if (active) { i = __builtin_ctz(mask); mask &= (mask - 1u); }
        // bit i = it*4+e ; elem t = (it*256+tid)*4+e
        const int t = ((i >> 2) << 10) + (tid << 2) + (i & 3);
        if (active) {
            const float val = m[t >> 5];        // candidate == its segment max
            const int l = max(t - RADIUS, 0);
            const int r = min(t + RADIUS, NT - 1);
            const int il = l >> 5, ir = r >> 5;
            // tier1: interior full segments il+1..ir-1 (<=9), includes own seg
            float iv[9];
#pragma unroll
            for (int j = 0; j < 9; ++j) {
                const int idx = il + 1 + j;
                const float mv = m[min(idx, NT / 32 - 1)];
                iv[j] = (idx < ir) ? mv : 0.0f;
            }
            float im = iv[0];
#pragma unroll
            for (int j = 1; j < 9; ++j) im = fmaxf(im, iv[j]);
            if (!(im > val)) {
                // tier2: superset edges at float4 granularity
                const int bl = l >> 2, br = r >> 2;
                const int hend = (il + 1) << 3;   // head blocks: bl..hend-1
                const int tst = ir << 3;          // tail blocks: tst..br
                float hv[8], tv[8];
#pragma unroll
                for (int j = 0; j < 8; ++j) {
                    int idx = bl + j;
                    float mv = m4[min(idx, NT / 4 - 1)];
                    hv[j] = (idx < hend) ? mv : 0.0f;
                    idx = tst + j;
                    mv = m4[min(idx, NT / 4 - 1)];
                    tv[j] = (idx <= br) ? mv : 0.0f;
                }
                float sup = im;
#pragma unroll
                for (int j = 0; j < 8; ++j) sup = fmaxf(sup, fmaxf(hv[j], tv[j]));
                bool acc = false;
                if (sup <= val) {
                    acc = true;                   // superset max == val -> exact
                } else if ((l & 3) != 0 || (r & 3) != 3) {
                    // tier3 (rare): fringe elems (superset \ window) might be
                    // the only ones > val. Rebuild exact window max: interior
                    // + edge blocks excluding bl/br + exact parts of bl/br.
                    float ex = im;
#pragma unroll
                    for (int j = 1; j < 8; ++j) ex = fmaxf(ex, hv[j]);
#pragma unroll
                    for (int j = 0; j < 8; ++j)
                        ex = fmaxf(ex, (tst + j < br) ? tv[j] : 0.0f);
                    const int he = min(bl * 4 + 3, r);
                    for (int u = l; u <= he; ++u) ex = fmaxf(ex, fabsf(grow[u]));
                    const int ts2 = max(br * 4, l);
                    for (int u = ts2; u <= r; ++u) ex = fmaxf(ex, fabsf(grow[u]));
                    if (ex <= val) acc = true;
                }
                if (acc) {
                    const unsigned long long key =
                        ((unsigned long long)__float_as_uint(val) << 32) |
                        (unsigned)(NT - 1 - t);
                    if (key > k1) { k2 = k1; k1 = key; }
                    else if (key > k2) { k2 = key; }
                }
            }
        }
    }

    // ---- P3: top-2 reduction (wave shuffle, then 4 waves via LDS) ----
#pragma unroll
    for (int off = 32; off >= 1; off >>= 1) {
        unsigned long long o1 = __shfl_down(k1, off);
        unsigned long long o2 = __shfl_down(k2, off);
        unsigned long long hi = (k1 > o1) ? k1 : o1;
        unsigned long long lo = (k1 > o1) ? o1 : k1;
        unsigned long long s2 = (k2 > o2) ? k2 : o2;
        k1 = hi;
        k2 = (lo > s2) ? lo : s2;
    }
    const int wave = tid >> 6;
    if ((tid & 63) == 0) { wred[wave * 2] = k1; wred[wave * 2 + 1] = k2; }
    __syncthreads();

    if (tid == 0) {
        unsigned long long a1 = wred[0], a2 = wred[1];
        for (int w = 1; w < 4; ++w) {
            unsigned long long o1 = wred[w * 2], o2 = wred[w * 2 + 1];
            unsigned long long hi = (a1 > o1) ? a1 : o1;
            unsigned long long lo = (a1 > o1) ? o1 : a1;
            unsigned long long s2 = (a2 > o2) ? a2 : o2;
            a1 = hi;
            a2 = (lo > s2) ? lo : s2;
        }
        float s1v, s2v; int i1, i2;
        if (a1 == 0ull) { s1v = 0.0f; i1 = 0; }
        else {
            s1v = __uint_as_float((unsigned)(a1 >> 32));
            i1 = (NT - 1) - (int)(a1 & 0xffffffffull);
        }
        if (a2 == 0ull) {   // <2 peaks: second entry is first zero-score slot
            s2v = 0.0f;
            i2 = (i1 == 0) ? 1 : 0;
        } else {
            s2v = __uint_as_float((unsigned)(a2 >> 32));
            i2 = (NT - 1) - (int)(a2 & 0xffffffffull);
        }
        out[row * 2 + 0] = s1v;
        out[row * 2 + 1] = s2v;
        float* oi = out + (size_t)nrows * 2;
        oi[row * 2 + 0] = (float)i1;
        oi[row * 2 + 1] = (float)i2;
    }
}

extern "C" void kernel_launch(void* const* d_in, const int* in_sizes, int n_in,
                              void* d_out, int out_size, void* d_ws, size_t ws_size,
                              hipStream_t stream) {
    const float* x = (const float*)d_in[0];
    // d_in[1] = nlag (unused by the reference)
    float* out = (float*)d_out;
    const int nrows = in_sizes[0] / NT;  // 32*3*64 = 6144
    detect_peaks_kernel<<<nrows, NTHREADS, 0, stream>>>(x, out, nrows);
}